// Round 4
// baseline (203.336 us; speedup 1.0000x reference)
//
#include <hip/hip_runtime.h>
#include <hip/hip_cooperative_groups.h>

namespace cg = cooperative_groups;

// EncoderBlock: gather(x, idx) -> per-o GEMM (512x128 @ K=512) + bias
//               -> BatchNorm over B=512 -> SiLU.
// R4: K2 eliminated. prepW (regular launch, Wt2 crosses kernel boundary) +
//     ONE cooperative kernel: GEMM+stats -> threadfence+grid.sync ->
//     scale/shift -> normalize acc registers -> fp32 out. No y round-trip.

typedef __attribute__((ext_vector_type(8))) __bf16 bf16x8;
typedef __attribute__((ext_vector_type(4))) __bf16 bf16x4;
typedef __attribute__((ext_vector_type(4))) float  f32x4;

#define B_SZ   512
#define N_IN   64
#define D_IN   128
#define FEAT   8192            // 64 * 128
#define LDA    40              // A LDS row stride (bf16): 80B, 16B-aligned
#define LDT    132             // prepW transpose tile row stride (bf16, 8B-aligned rows)

// ---- prepW: W fp32 [o][kidx4][d128][e128] -> Wt2 bf16 [o][kk16][e128][k32]
// where global k = kidx*128 + d, kk = k>>5, kin = k&31.
__global__ __launch_bounds__(256, 2)
void prep_w_kernel(const float* __restrict__ W, __bf16* __restrict__ Wt2)
{
    __shared__ __bf16 T[128 * LDT];
    const int o    = blockIdx.x >> 2;
    const int kidx = blockIdx.x & 3;
    const int tid  = threadIdx.x;

    // phase 1: coalesced read of slab [128 d][128 e], cvt, store d-major tile
#pragma unroll
    for (int it = 0; it < 16; ++it) {
        const int lin = it * 1024 + tid * 4;
        const int d   = lin >> 7;
        const int e   = lin & 127;
        f32x4 v = *(const f32x4*)(W + (((o * 4 + kidx) * 128 + d) * 128 + e));
        bf16x4 b;
        b[0] = (__bf16)v[0]; b[1] = (__bf16)v[1];
        b[2] = (__bf16)v[2]; b[3] = (__bf16)v[3];
        *(bf16x4*)&T[d * LDT + e] = b;
    }
    __syncthreads();

    // phase 2: write k-major: task = (e, dc): 8 consecutive d for one e
#pragma unroll
    for (int it = 0; it < 8; ++it) {
        const int task = it * 256 + tid;
        const int e    = task >> 4;
        const int dc   = task & 15;
        bf16x8 v;
#pragma unroll
        for (int j = 0; j < 8; ++j) v[j] = T[(dc * 8 + j) * LDT + e];
        const int kk  = kidx * 4 + (dc >> 2);
        const int kin = (dc & 3) * 8;
        *(bf16x8*)(Wt2 + (((o * 16 + kk) * 128 + e) * 32 + kin)) = v;
    }
}

__global__ __launch_bounds__(256, 2)
void gemm_bn_silu_kernel(const float* __restrict__ x, const __bf16* __restrict__ Wt2,
                         const float* __restrict__ bias, const int* __restrict__ idxp,
                         const float* __restrict__ gamma, const float* __restrict__ beta,
                         float* __restrict__ out, float* __restrict__ psum,
                         float* __restrict__ psq)
{
    __shared__ __bf16 Alds[2][64 * LDA];   // double-buffered A tile [64 m][32 k]
    __shared__ float sscale[128];
    __shared__ float sshift[128];

    const int bx   = blockIdx.x;
    const int o    = bx >> 3;       // output group
    const int bt   = bx & 7;        // batch tile (64 rows)
    const int b0   = bt * 64;
    const int tid  = threadIdx.x;
    const int wave = tid >> 6;      // wave covers n in [wave*32, wave*32+32)
    const int lane = tid & 63;
    const int lam  = lane & 15;
    const int quad = lane >> 4;
    const int nbase = wave * 32;

    int rsel[4];
#pragma unroll
    for (int k = 0; k < 4; ++k) rsel[k] = idxp[o * 4 + k];

    const f32x4 zero4 = {0.f, 0.f, 0.f, 0.f};
    f32x4 acc[4][2];
#pragma unroll
    for (int mi = 0; mi < 4; ++mi)
#pragma unroll
        for (int ni = 0; ni < 2; ++ni) acc[mi][ni] = zero4;

    // A staging map: 4 threads per row, 8 floats each
    const int m_a = tid >> 2;
    const int ca  = (tid & 3) * 8;

    // B fragment pointer: lane reads 16B; the wave's 64 lanes cover one
    // contiguous 1KB chunk of Wt2[o][kk][nbase..nbase+32][0..32).
    const __bf16* bptr = Wt2 + ((size_t)(o * 16) * 128 + nbase + lam) * 32 + quad * 8;

    // prologue: global A loads for kk=0
    f32x4 xv0, xv1;
    {
        const int r = rsel[0];
        const float* xa = x + (((b0 + m_a) * N_IN + r) * D_IN + ca);
        xv0 = *(const f32x4*)(xa + 0);
        xv1 = *(const f32x4*)(xa + 4);
    }

    for (int kk = 0; kk < 16; ++kk) {
        // cvt + store current A tile
        bf16x8 p;
        p[0] = (__bf16)xv0[0]; p[1] = (__bf16)xv0[1];
        p[2] = (__bf16)xv0[2]; p[3] = (__bf16)xv0[3];
        p[4] = (__bf16)xv1[0]; p[5] = (__bf16)xv1[1];
        p[6] = (__bf16)xv1[2]; p[7] = (__bf16)xv1[3];
        const int buf = kk & 1;
        *(bf16x8*)&Alds[buf][m_a * LDA + ca] = p;
        __syncthreads();

        // prefetch next A tile (all loads consumed before next barrier)
        if (kk < 15) {
            const int kn = kk + 1;
            const int r  = rsel[kn >> 2];
            const int d0 = (kn & 3) * 32;
            const float* xa = x + (((b0 + m_a) * N_IN + r) * D_IN + d0 + ca);
            xv0 = *(const f32x4*)(xa + 0);
            xv1 = *(const f32x4*)(xa + 4);
        }

        // B fragments: direct global (L2/L3-resident, perfectly coalesced)
        bf16x8 bfv[2];
#pragma unroll
        for (int ni = 0; ni < 2; ++ni)
            bfv[ni] = *(const bf16x8*)(bptr + ((size_t)kk * 128 + ni * 16) * 32);

        // A fragments from LDS
        bf16x8 af[4];
#pragma unroll
        for (int mi = 0; mi < 4; ++mi)
            af[mi] = *(const bf16x8*)&Alds[buf][(mi * 16 + lam) * LDA + quad * 8];

#pragma unroll
        for (int mi = 0; mi < 4; ++mi)
#pragma unroll
            for (int ni = 0; ni < 2; ++ni)
                acc[mi][ni] = __builtin_amdgcn_mfma_f32_16x16x32_bf16(
                    af[mi], bfv[ni], acc[mi][ni], 0, 0, 0);
    }

    // ---- bias + column partial stats over this block's 64 rows ----
    float bvals[2];
#pragma unroll
    for (int ni = 0; ni < 2; ++ni)
        bvals[ni] = bias[o * 128 + nbase + ni * 16 + lam];

#pragma unroll
    for (int mi = 0; mi < 4; ++mi)
#pragma unroll
        for (int ni = 0; ni < 2; ++ni)
#pragma unroll
            for (int rr = 0; rr < 4; ++rr) acc[mi][ni][rr] += bvals[ni];

#pragma unroll
    for (int ni = 0; ni < 2; ++ni) {
        float s = 0.f, q = 0.f;
#pragma unroll
        for (int mi = 0; mi < 4; ++mi)
#pragma unroll
            for (int rr = 0; rr < 4; ++rr) {
                const float v = acc[mi][ni][rr];
                s += v; q += v * v;
            }
        s += __shfl_xor(s, 16); s += __shfl_xor(s, 32);
        q += __shfl_xor(q, 16); q += __shfl_xor(q, 32);
        if (quad == 0) {
            const int e = nbase + ni * 16 + lam;
            psum[(o * 8 + bt) * 128 + e] = s;
            psq [(o * 8 + bt) * 128 + e] = q;
        }
    }

    // ---- grid-wide: make partials visible, wait for all blocks ----
    __threadfence();
    cg::this_grid().sync();

    // ---- reduce this o's 8 slots -> scale/shift (redundant per block) ----
    if (tid < 128) {
        float s = 0.f, q = 0.f;
#pragma unroll
        for (int sl = 0; sl < 8; ++sl) {
            s += psum[(o * 8 + sl) * 128 + tid];
            q += psq [(o * 8 + sl) * 128 + tid];
        }
        const float mean = s * (1.0f / 512.0f);
        const float var  = q * (1.0f / 512.0f) - mean * mean;
        const float rstd = rsqrtf(var + 1e-5f);
        const float sc   = rstd * gamma[o * 128 + tid];
        sscale[tid] = sc;
        sshift[tid] = beta[o * 128 + tid] - mean * sc;
    }
    __syncthreads();

    // ---- normalize registers + SiLU -> fp32 out ----
    // D layout: row = quad*4 + rr, col = lam (per 16x16 tile)
#pragma unroll
    for (int mi = 0; mi < 4; ++mi) {
        const int mrow = b0 + mi * 16 + quad * 4;
#pragma unroll
        for (int ni = 0; ni < 2; ++ni) {
            const int cl = nbase + ni * 16 + lam;   // column within o's 128
            const float sc = sscale[cl];
            const float sh = sshift[cl];
#pragma unroll
            for (int rr = 0; rr < 4; ++rr) {
                const float xn = acc[mi][ni][rr] * sc + sh;
                out[(size_t)(mrow + rr) * FEAT + o * 128 + cl] =
                    xn / (1.0f + __expf(-xn));
            }
        }
    }
}

extern "C" void kernel_launch(void* const* d_in, const int* in_sizes, int n_in,
                              void* d_out, int out_size, void* d_ws, size_t ws_size,
                              hipStream_t stream)
{
    const float* x     = (const float*)d_in[0];
    const float* W     = (const float*)d_in[1];
    const float* bias  = (const float*)d_in[2];
    const float* gamma = (const float*)d_in[3];
    const float* beta  = (const float*)d_in[4];
    const int*   idx   = (const int*)d_in[5];
    float* out = (float*)d_out;

    // ws layout: Wt2 bf16 (8 MiB) | psum (256 KiB) | psq (256 KiB)
    __bf16* Wt2  = (__bf16*)d_ws;
    float*  psum = (float*)(Wt2 + (size_t)64 * 512 * 128);
    float*  psq  = psum + 64 * 8 * 128;

    prep_w_kernel<<<dim3(256), dim3(256), 0, stream>>>(W, Wt2);

    void* args[] = { (void*)&x, (void*)&Wt2, (void*)&bias, (void*)&idx,
                     (void*)&gamma, (void*)&beta, (void*)&out,
                     (void*)&psum, (void*)&psq };
    hipLaunchCooperativeKernel((const void*)gemm_bn_silu_kernel,
                               dim3(512), dim3(256), args, 0, stream);
}

// Round 5
// 109.315 us; speedup vs baseline: 1.8601x; 1.8601x over previous
//
#include <hip/hip_runtime.h>

// EncoderBlock: gather(x, idx) -> per-o GEMM (512x128 @ K=512) + bias
//               -> BatchNorm over B=512 -> SiLU.
// R5: revert to R3 structure (R4's cooperative grid.sync measured +95us).
//     prepW: W fp32 -> Wt2 bf16 [o][kk16][e128][k32] (k-major for coalesced
//     B fragments). K1: MFMA GEMM, A double-buffered LDS, B direct global,
//     y bf16 + column partial stats to ws. K2: reduce partials -> BN+SiLU,
//     nontemporal fp32 out stores (out never re-read).

typedef __attribute__((ext_vector_type(8))) __bf16 bf16x8;
typedef __attribute__((ext_vector_type(4))) __bf16 bf16x4;
typedef __attribute__((ext_vector_type(4))) float  f32x4;

#define B_SZ   512
#define N_IN   64
#define D_IN   128
#define FEAT   8192            // 64 * 128
#define LDA    40              // A LDS row stride (bf16): 80B, 16B-aligned
#define LDT    132             // prepW transpose tile row stride (bf16)

// ---- prepW: W fp32 [o][kidx4][d128][e128] -> Wt2 bf16 [o][kk16][e128][k32]
// where global k = kidx*128 + d, kk = k>>5, kin = k&31.
__global__ __launch_bounds__(256, 2)
void prep_w_kernel(const float* __restrict__ W, __bf16* __restrict__ Wt2)
{
    __shared__ __bf16 T[128 * LDT];
    const int o    = blockIdx.x >> 2;
    const int kidx = blockIdx.x & 3;
    const int tid  = threadIdx.x;

    // phase 1: coalesced read of slab [128 d][128 e], cvt, store d-major tile
#pragma unroll
    for (int it = 0; it < 16; ++it) {
        const int lin = it * 1024 + tid * 4;
        const int d   = lin >> 7;
        const int e   = lin & 127;
        f32x4 v = *(const f32x4*)(W + (((o * 4 + kidx) * 128 + d) * 128 + e));
        bf16x4 b;
        b[0] = (__bf16)v[0]; b[1] = (__bf16)v[1];
        b[2] = (__bf16)v[2]; b[3] = (__bf16)v[3];
        *(bf16x4*)&T[d * LDT + e] = b;
    }
    __syncthreads();

    // phase 2: write k-major: task = (e, dc): 8 consecutive d for one e
#pragma unroll
    for (int it = 0; it < 8; ++it) {
        const int task = it * 256 + tid;
        const int e    = task >> 4;
        const int dc   = task & 15;
        bf16x8 v;
#pragma unroll
        for (int j = 0; j < 8; ++j) v[j] = T[(dc * 8 + j) * LDT + e];
        const int kk  = kidx * 4 + (dc >> 2);
        const int kin = (dc & 3) * 8;
        *(bf16x8*)(Wt2 + (((o * 16 + kk) * 128 + e) * 32 + kin)) = v;
    }
}

__global__ __launch_bounds__(256, 2)
void gemm_stats_kernel(const float* __restrict__ x, const __bf16* __restrict__ Wt2,
                       const float* __restrict__ bias, const int* __restrict__ idxp,
                       __bf16* __restrict__ y, float* __restrict__ psum,
                       float* __restrict__ psq)
{
    __shared__ __bf16 Alds[2][64 * LDA];   // double-buffered A tile [64 m][32 k]

    const int bx   = blockIdx.x;
    const int o    = bx >> 3;       // output group
    const int bt   = bx & 7;        // batch tile (64 rows)
    const int b0   = bt * 64;
    const int tid  = threadIdx.x;
    const int wave = tid >> 6;      // wave covers n in [wave*32, wave*32+32)
    const int lane = tid & 63;
    const int lam  = lane & 15;
    const int quad = lane >> 4;
    const int nbase = wave * 32;

    int rsel[4];
#pragma unroll
    for (int k = 0; k < 4; ++k) rsel[k] = idxp[o * 4 + k];

    const f32x4 zero4 = {0.f, 0.f, 0.f, 0.f};
    f32x4 acc[4][2];
#pragma unroll
    for (int mi = 0; mi < 4; ++mi)
#pragma unroll
        for (int ni = 0; ni < 2; ++ni) acc[mi][ni] = zero4;

    // A staging map: 4 threads per row, 8 floats each
    const int m_a = tid >> 2;
    const int ca  = (tid & 3) * 8;

    // B fragment pointer: lane reads 16B; the wave's 64 lanes cover one
    // contiguous 1KB chunk of Wt2[o][kk][nbase..nbase+32][0..32).
    const __bf16* bptr = Wt2 + ((size_t)(o * 16) * 128 + nbase + lam) * 32 + quad * 8;

    // prologue: global A loads for kk=0
    f32x4 xv0, xv1;
    {
        const int r = rsel[0];
        const float* xa = x + (((b0 + m_a) * N_IN + r) * D_IN + ca);
        xv0 = *(const f32x4*)(xa + 0);
        xv1 = *(const f32x4*)(xa + 4);
    }

    for (int kk = 0; kk < 16; ++kk) {
        // cvt + store current A tile
        bf16x8 p;
        p[0] = (__bf16)xv0[0]; p[1] = (__bf16)xv0[1];
        p[2] = (__bf16)xv0[2]; p[3] = (__bf16)xv0[3];
        p[4] = (__bf16)xv1[0]; p[5] = (__bf16)xv1[1];
        p[6] = (__bf16)xv1[2]; p[7] = (__bf16)xv1[3];
        const int buf = kk & 1;
        *(bf16x8*)&Alds[buf][m_a * LDA + ca] = p;
        __syncthreads();

        // prefetch next A tile (all loads consumed before next barrier)
        if (kk < 15) {
            const int kn = kk + 1;
            const int r  = rsel[kn >> 2];
            const int d0 = (kn & 3) * 32;
            const float* xa = x + (((b0 + m_a) * N_IN + r) * D_IN + d0 + ca);
            xv0 = *(const f32x4*)(xa + 0);
            xv1 = *(const f32x4*)(xa + 4);
        }

        // B fragments: direct global (L2/L3-resident, perfectly coalesced)
        bf16x8 bfv[2];
#pragma unroll
        for (int ni = 0; ni < 2; ++ni)
            bfv[ni] = *(const bf16x8*)(bptr + ((size_t)kk * 128 + ni * 16) * 32);

        // A fragments from LDS
        bf16x8 af[4];
#pragma unroll
        for (int mi = 0; mi < 4; ++mi)
            af[mi] = *(const bf16x8*)&Alds[buf][(mi * 16 + lam) * LDA + quad * 8];

#pragma unroll
        for (int mi = 0; mi < 4; ++mi)
#pragma unroll
            for (int ni = 0; ni < 2; ++ni)
                acc[mi][ni] = __builtin_amdgcn_mfma_f32_16x16x32_bf16(
                    af[mi], bfv[ni], acc[mi][ni], 0, 0, 0);
    }

    // ---- epilogue: bias, y store (bf16), column partial stats ----
    float bvals[2];
#pragma unroll
    for (int ni = 0; ni < 2; ++ni)
        bvals[ni] = bias[o * 128 + nbase + ni * 16 + lam];

#pragma unroll
    for (int mi = 0; mi < 4; ++mi)
#pragma unroll
        for (int ni = 0; ni < 2; ++ni)
#pragma unroll
            for (int rr = 0; rr < 4; ++rr) acc[mi][ni][rr] += bvals[ni];

    // y store: D[row=quad*4+rr][col=lam]
#pragma unroll
    for (int mi = 0; mi < 4; ++mi) {
        const int mrow = b0 + mi * 16 + quad * 4;
#pragma unroll
        for (int ni = 0; ni < 2; ++ni) {
            const int col = o * 128 + nbase + ni * 16 + lam;
#pragma unroll
            for (int rr = 0; rr < 4; ++rr)
                y[(mrow + rr) * FEAT + col] = (__bf16)acc[mi][ni][rr];
        }
    }

    // column partials over this block's 64 rows (fp32, pre-rounding)
#pragma unroll
    for (int ni = 0; ni < 2; ++ni) {
        float s = 0.f, q = 0.f;
#pragma unroll
        for (int mi = 0; mi < 4; ++mi)
#pragma unroll
            for (int rr = 0; rr < 4; ++rr) {
                const float v = acc[mi][ni][rr];
                s += v; q += v * v;
            }
        s += __shfl_xor(s, 16); s += __shfl_xor(s, 32);
        q += __shfl_xor(q, 16); q += __shfl_xor(q, 32);
        if (quad == 0) {
            const int e = nbase + ni * 16 + lam;
            psum[(o * 8 + bt) * 128 + e] = s;
            psq [(o * 8 + bt) * 128 + e] = q;
        }
    }
}

__global__ __launch_bounds__(256, 4)
void norm_silu_kernel(const __bf16* __restrict__ y, const float* __restrict__ psum,
                      const float* __restrict__ psq, const float* __restrict__ gamma,
                      const float* __restrict__ beta, float* __restrict__ out)
{
    __shared__ float sscale[128];
    __shared__ float sshift[128];
    const int o   = blockIdx.x >> 3;
    const int bc  = blockIdx.x & 7;   // 64-batch chunk
    const int tid = threadIdx.x;

    if (tid < 128) {
        float s = 0.f, q = 0.f;
#pragma unroll
        for (int sl = 0; sl < 8; ++sl) {
            s += psum[(o * 8 + sl) * 128 + tid];
            q += psq [(o * 8 + sl) * 128 + tid];
        }
        const float mean = s * (1.0f / 512.0f);
        const float var  = q * (1.0f / 512.0f) - mean * mean;
        const float rstd = rsqrtf(var + 1e-5f);
        const float sc   = rstd * gamma[o * 128 + tid];
        sscale[tid] = sc;
        sshift[tid] = beta[o * 128 + tid] - mean * sc;
    }
    __syncthreads();

#pragma unroll
    for (int it = 0; it < 4; ++it) {
        const int lin = it * 2048 + tid * 8;
        const int bl  = lin >> 7;
        const int e   = lin & 127;
        const int g   = (bc * 64 + bl) * FEAT + o * 128 + e;
        bf16x8 y8 = *(const bf16x8*)&y[g];
        f32x4 ov0, ov1;
#pragma unroll
        for (int j = 0; j < 4; ++j) {
            const float v  = (float)y8[j];
            const float xn = v * sscale[e + j] + sshift[e + j];
            ov0[j] = xn / (1.0f + __expf(-xn));
        }
#pragma unroll
        for (int j = 0; j < 4; ++j) {
            const float v  = (float)y8[4 + j];
            const float xn = v * sscale[e + 4 + j] + sshift[e + 4 + j];
            ov1[j] = xn / (1.0f + __expf(-xn));
        }
        __builtin_nontemporal_store(ov0, (f32x4*)&out[g]);
        __builtin_nontemporal_store(ov1, (f32x4*)&out[g + 4]);
    }
}

extern "C" void kernel_launch(void* const* d_in, const int* in_sizes, int n_in,
                              void* d_out, int out_size, void* d_ws, size_t ws_size,
                              hipStream_t stream)
{
    const float* x     = (const float*)d_in[0];
    const float* W     = (const float*)d_in[1];
    const float* bias  = (const float*)d_in[2];
    const float* gamma = (const float*)d_in[3];
    const float* beta  = (const float*)d_in[4];
    const int*   idx   = (const int*)d_in[5];
    float* out = (float*)d_out;

    // ws layout: y bf16 (8 MiB) | Wt2 bf16 (8 MiB) | psum (256 KiB) | psq
    __bf16* y    = (__bf16*)d_ws;
    __bf16* Wt2  = y + (size_t)B_SZ * FEAT;
    float*  psum = (float*)(Wt2 + (size_t)64 * 512 * 128);
    float*  psq  = psum + 64 * 8 * 128;

    prep_w_kernel<<<dim3(256), dim3(256), 0, stream>>>(W, Wt2);
    gemm_stats_kernel<<<dim3(512), dim3(256), 0, stream>>>(x, Wt2, bias, idx, y, psum, psq);
    norm_silu_kernel<<<dim3(512), dim3(256), 0, stream>>>(y, psum, psq, gamma, beta, out);
}